// Round 14
// baseline (571.754 us; speedup 1.0000x reference)
//
#include <hip/hip_runtime.h>

#define T_TOTAL 131072
#define SEGLEN  64
#define WARM    64
#define GSEG    4
#define NBLK    (T_TOTAL / (SEGLEN * GSEG))   // 512

typedef __attribute__((ext_vector_type(8))) short short8;
typedef __attribute__((ext_vector_type(8))) unsigned short ushort8;
typedef __attribute__((ext_vector_type(4))) unsigned short ushort4v;
typedef __attribute__((ext_vector_type(4))) float f32x4;

__device__ __forceinline__ float sigf(float x) {
  return __builtin_amdgcn_rcpf(1.f + __expf(-x));
}
__device__ __forceinline__ float tanhfast(float x) {
  return 1.f - 2.f * __builtin_amdgcn_rcpf(__expf(2.f * x) + 1.f);
}
__device__ __forceinline__ unsigned short f2bf(float x) {
  unsigned u = __float_as_uint(x);
  return (unsigned short)((u + 0x7FFFu + ((u >> 16) & 1u)) >> 16);
}
__device__ __forceinline__ float bf2f(unsigned short u) {
  return __uint_as_float(((unsigned)u) << 16);
}
__device__ __forceinline__ void load_lds16(const void* g, void* l) {
  __builtin_amdgcn_global_load_lds(
      (const __attribute__((address_space(1))) void*)g,
      (__attribute__((address_space(3))) void*)l, 16, 0, 0);
}

// ---------- pad x [T][8] f32 -> [T][32] bf16; col 8 = 1.0 (bias rides Wih0)
__global__ __launch_bounds__(256) void pad_x(
    const float* __restrict__ x, unsigned short* __restrict__ xp)
{
  const int t = blockIdx.x * 256 + threadIdx.x;
  const float4 a = reinterpret_cast<const float4*>(x)[t * 2];
  const float4 b = reinterpret_cast<const float4*>(x)[t * 2 + 1];
  ushort8 v;
  v[0] = f2bf(a.x); v[1] = f2bf(a.y); v[2] = f2bf(a.z); v[3] = f2bf(a.w);
  v[4] = f2bf(b.x); v[5] = f2bf(b.y); v[6] = f2bf(b.z); v[7] = f2bf(b.w);
  ushort8 z = {0, 0, 0, 0, 0, 0, 0, 0};
  ushort8 z1 = {0x3F80, 0, 0, 0, 0, 0, 0, 0};
  ushort8* o = reinterpret_cast<ushort8*>(xp) + (size_t)t * 4;
  o[0] = v; o[1] = z1; o[2] = z; o[3] = z;
}

// ---------- layer-0 LSTM, 4 segments per block via MFMA columns.
// SB=16 -> LDS 45 KB -> 2 blocks/CU (NBLK=512): cross-block latency hiding.
__global__ __launch_bounds__(256) __attribute__((amdgpu_waves_per_eu(1)))
void lstm_l0(
    const unsigned short* __restrict__ xpad,
    unsigned short* __restrict__ hout,
    const float* __restrict__ Whh, const float* __restrict__ Wih,
    const float* __restrict__ bih, const float* __restrict__ bhh)
{
  constexpr int SB = 16;
  __shared__ __align__(16) unsigned short inbuf[2][SB][4][32];   // 8 KB
  __shared__ __align__(16) unsigned short hhist[2][SB][4][144];  // 36 KB
  const int tid = threadIdx.x;
  const int l = tid & 63, w = tid >> 6;
  const int c = l & 15, q = l >> 4;
  const int sl = c >> 2, r = c & 3;
  const int uA = w * 32 + r * 4 + q;
  const int uB = uA + 16;
  const int s0 = blockIdx.x * GSEG;
  const bool zw = (blockIdx.x == 0) && (sl == 0);

  short8 af[8][4];
#pragma unroll
  for (int ti = 0; ti < 8; ++ti) {
    const int rp = (w * 8 + ti) * 16 + c;
    const int jm = rp >> 2, g = rp & 3;
    const float* wr = Whh + (size_t)(g * 128 + jm) * 128 + q * 8;
#pragma unroll
    for (int kc = 0; kc < 4; ++kc) {
      short8 v;
#pragma unroll
      for (int e = 0; e < 8; ++e) v[e] = (short)f2bf(wr[kc * 32 + e]);
      af[ti][kc] = v;
    }
  }
  short8 afi[8];
#pragma unroll
  for (int ti = 0; ti < 8; ++ti) {
    const int rp = (w * 8 + ti) * 16 + c;
    const int jm = rp >> 2, g = rp & 3;
    short8 v;
#pragma unroll
    for (int e = 0; e < 8; ++e) {
      const int k = q * 8 + e;
      float wv = 0.f;
      if (k < 8) wv = Wih[(size_t)(g * 128 + jm) * 8 + k];
      else if (k == 8) wv = bih[g * 128 + jm] + bhh[g * 128 + jm];
      v[e] = (short)f2bf(wv);
    }
    afi[ti] = v;
  }
  const f32x4 zero4 = {0.f, 0.f, 0.f, 0.f};
  const int nb = (SEGLEN + WARM) / SB;   // 8

  float cA = 0.f, cB = 0.f;
  for (int i = tid; i < 4 * 128; i += 256) hhist[1][SB - 1][i >> 7][i & 127] = 0;

  // prologue: stage sub-block 0 (256 slots: row16 x seg4 x oct4)
  {
    const int row = tid >> 4, sg = (tid >> 2) & 3, oct = tid & 3;
    int t = (s0 + sg) * SEGLEN - WARM + row;
    t = t < 0 ? 0 : t;
    load_lds16(xpad + (size_t)t * 32 + oct * 8,
               &inbuf[0][0][0][0] + (size_t)(tid & ~63) * 8);
  }
  asm volatile("s_waitcnt vmcnt(0) lgkmcnt(0)" ::: "memory");
  __builtin_amdgcn_sched_barrier(0);
  __builtin_amdgcn_s_barrier();
  __builtin_amdgcn_sched_barrier(0);

  for (int bi = 0; bi < nb; ++bi) {
    const int pb = bi & 1;
    if (bi + 1 < nb) {
      const int row = tid >> 4, sg = (tid >> 2) & 3, oct = tid & 3;
      int t = (s0 + sg) * SEGLEN - WARM + (bi + 1) * SB + row;
      t = t < 0 ? 0 : t;
      load_lds16(xpad + (size_t)t * 32 + oct * 8,
                 &inbuf[pb ^ 1][0][0][0] + (size_t)(tid & ~63) * 8);
    }
    if (bi >= WARM / SB + 1) {  // flush sub-block bi-1
      const int lt0 = (bi - 1) * SB - WARM;
#pragma unroll
      for (int it = 0; it < 4; ++it) {
        const int slot = it * 256 + tid;
        const int frow = slot >> 6, fsl = (slot >> 4) & 3, foc = slot & 15;
        const ushort8 hv = *reinterpret_cast<const ushort8*>(&hhist[pb ^ 1][frow][fsl][foc * 8]);
        *reinterpret_cast<ushort8*>(
            hout + ((size_t)(s0 + fsl) * SEGLEN + lt0 + frow) * 128 + foc * 8) = hv;
      }
    }

    for (int s = 0; s < SB; ++s) {
      const int lt = bi * SB + s - WARM;
      const unsigned short* hr = s ? &hhist[pb][s - 1][sl][0] : &hhist[pb ^ 1][SB - 1][sl][0];
      short8 bh[4];
#pragma unroll
      for (int kc = 0; kc < 4; ++kc)
        bh[kc] = *reinterpret_cast<const short8*>(hr + kc * 32 + q * 8);
      const short8 bx = *reinterpret_cast<const short8*>(&inbuf[pb][s][sl][q * 8]);

#define CHAIN0(ti) \
      f32x4 z##ti; { \
        f32x4 a = __builtin_amdgcn_mfma_f32_16x16x32_bf16(afi[ti], bx, zero4, 0, 0, 0); \
        a = __builtin_amdgcn_mfma_f32_16x16x32_bf16(af[ti][0], bh[0], a, 0, 0, 0); \
        a = __builtin_amdgcn_mfma_f32_16x16x32_bf16(af[ti][1], bh[1], a, 0, 0, 0); \
        a = __builtin_amdgcn_mfma_f32_16x16x32_bf16(af[ti][2], bh[2], a, 0, 0, 0); \
        z##ti = __builtin_amdgcn_mfma_f32_16x16x32_bf16(af[ti][3], bh[3], a, 0, 0, 0); }
      CHAIN0(0) CHAIN0(1) CHAIN0(2) CHAIN0(3)
      CHAIN0(4) CHAIN0(5) CHAIN0(6) CHAIN0(7)
#undef CHAIN0
      const bool m1 = (r & 1) != 0, m2 = (r & 2) != 0;
      f32x4 zA, zB;
#pragma unroll
      for (int k = 0; k < 4; ++k) {
        const float v01 = m1 ? z1[k] : z0[k];
        const float v23 = m1 ? z3[k] : z2[k];
        zA[k] = m2 ? v23 : v01;
        const float v45 = m1 ? z5[k] : z4[k];
        const float v67 = m1 ? z7[k] : z6[k];
        zB[k] = m2 ? v67 : v45;
      }
      const float igA = sigf(zA[0]), fgA = sigf(zA[1]);
      const float ggA = tanhfast(zA[2]), ogA = sigf(zA[3]);
      cA = fmaf(fgA, cA, igA * ggA);
      float hA = ogA * tanhfast(cA);
      const float igB = sigf(zB[0]), fgB = sigf(zB[1]);
      const float ggB = tanhfast(zB[2]), ogB = sigf(zB[3]);
      cB = fmaf(fgB, cB, igB * ggB);
      float hB = ogB * tanhfast(cB);
      if (zw && lt < 0) { cA = 0.f; cB = 0.f; hA = 0.f; hB = 0.f; }
      hhist[pb][s][sl][uA] = f2bf(hA);
      hhist[pb][s][sl][uB] = f2bf(hB);

      asm volatile("s_waitcnt lgkmcnt(0)" ::: "memory");
      __builtin_amdgcn_sched_barrier(0);
      __builtin_amdgcn_s_barrier();
      __builtin_amdgcn_sched_barrier(0);
    }

    asm volatile("s_waitcnt vmcnt(0)" ::: "memory");
    __builtin_amdgcn_sched_barrier(0);
    __builtin_amdgcn_s_barrier();
    __builtin_amdgcn_sched_barrier(0);
  }

  {  // epilogue flush
    const int pb = (nb - 1) & 1;
    const int lt0 = (nb - 1) * SB - WARM;
#pragma unroll
    for (int it = 0; it < 4; ++it) {
      const int slot = it * 256 + tid;
      const int frow = slot >> 6, fsl = (slot >> 4) & 3, foc = slot & 15;
      const ushort8 hv = *reinterpret_cast<const ushort8*>(&hhist[pb][frow][fsl][foc * 8]);
      *reinterpret_cast<ushort8*>(
          hout + ((size_t)(s0 + fsl) * SEGLEN + lt0 + frow) * 128 + foc * 8) = hv;
    }
  }
}

// ---------- pre1 projection: pre1[t][rp] = Wih1_perm@h0 + bias (bf16 out)
__global__ __launch_bounds__(256) void proj512(
    const unsigned short* __restrict__ h0, const float* __restrict__ Wih,
    const float* __restrict__ bih, const float* __restrict__ bhh,
    unsigned short* __restrict__ pre1)
{
  __shared__ __align__(16) unsigned short inr[128 * 128];
  __shared__ __align__(16) unsigned short Wl[128 * 128];
  __shared__ float badj[128];
  const int tid = threadIdx.x;
  const int l = tid & 63, w = tid >> 6;
  const int c = l & 15, q = l >> 4;
  const int tb = blockIdx.x >> 2, cb = blockIdx.x & 3;
  const size_t t0 = (size_t)tb * 128;

#pragma unroll
  for (int i = 0; i < 8; ++i) {
    const int slot = i * 256 + tid;
    const int rr = slot >> 4, o = slot & 15;
    const int so = (o + rr) & 15;
    load_lds16(h0 + (t0 + rr) * 128 + so * 8, &inr[0] + (i * 256 + (tid & ~63)) * 8);
  }
  for (int idx = tid; idx < 128 * 128; idx += 256) {
    const int n = idx >> 7, k = idx & 127;
    const int rp = cb * 128 + n;
    const int jm = rp >> 2, g = rp & 3;
    const float wv = Wih[(size_t)(g * 128 + jm) * 128 + k];
    const int so = ((k >> 3) + n) & 15;
    Wl[n * 128 + so * 8 + (k & 7)] = f2bf(wv);
  }
  if (tid < 128) {
    const int rp = cb * 128 + tid;
    const int jm = rp >> 2, g = rp & 3;
    badj[tid] = bih[g * 128 + jm] + bhh[g * 128 + jm];
  }
  asm volatile("s_waitcnt vmcnt(0)" ::: "memory");
  __syncthreads();

  short8 bw[8][4];
#pragma unroll
  for (int ct = 0; ct < 8; ++ct)
#pragma unroll
    for (int kc = 0; kc < 4; ++kc) {
      const int o = ((kc * 4 + q) + (ct * 16 + c)) & 15;
      bw[ct][kc] = *reinterpret_cast<const short8*>(&Wl[(ct * 16 + c) * 128 + o * 8]);
    }

#pragma unroll
  for (int rt2 = 0; rt2 < 2; ++rt2) {
    const int rt = w * 2 + rt2;
    short8 afr[4];
#pragma unroll
    for (int kc = 0; kc < 4; ++kc) {
      const int o = ((kc * 4 + q) - c) & 15;
      afr[kc] = *reinterpret_cast<const short8*>(&inr[(rt * 16 + c) * 128 + o * 8]);
    }
#pragma unroll
    for (int ct = 0; ct < 8; ++ct) {
      const float bb = badj[ct * 16 + c];
      f32x4 acc = {bb, bb, bb, bb};
#pragma unroll
      for (int kc = 0; kc < 4; ++kc)
        acc = __builtin_amdgcn_mfma_f32_16x16x32_bf16(afr[kc], bw[ct][kc], acc, 0, 0, 0);
#pragma unroll
      for (int rr = 0; rr < 4; ++rr)
        pre1[(t0 + rt * 16 + q * 4 + rr) * 512 + cb * 128 + ct * 16 + c] = f2bf(acc[rr]);
    }
  }
}

// ---------- layer-1 LSTM, 4 segments per block; SB=4, padded preb (42.5 KB).
__global__ __launch_bounds__(256) __attribute__((amdgpu_waves_per_eu(1)))
void lstm_l1(
    const unsigned short* __restrict__ pre,
    unsigned short* __restrict__ hout,
    const float* __restrict__ Whh)
{
  constexpr int SB = 4;
  __shared__ __align__(16) unsigned short preb[2][SB][4][520];   // 33.3 KB, pad kills 4-way
  __shared__ __align__(16) unsigned short hhist[2][SB][4][144];  // 9.2 KB
  const int tid = threadIdx.x;
  const int l = tid & 63, w = tid >> 6;
  const int c = l & 15, q = l >> 4;
  const int sl = c >> 2, r = c & 3;
  const int uA = w * 32 + r * 4 + q;
  const int uB = uA + 16;
  const int s0 = blockIdx.x * GSEG;
  const bool zw = (blockIdx.x == 0) && (sl == 0);

  short8 af[8][4];
#pragma unroll
  for (int ti = 0; ti < 8; ++ti) {
    const int rp = (w * 8 + ti) * 16 + c;
    const int jm = rp >> 2, g = rp & 3;
    const float* wr = Whh + (size_t)(g * 128 + jm) * 128 + q * 8;
#pragma unroll
    for (int kc = 0; kc < 4; ++kc) {
      short8 v;
#pragma unroll
      for (int e = 0; e < 8; ++e) v[e] = (short)f2bf(wr[kc * 32 + e]);
      af[ti][kc] = v;
    }
  }
  const f32x4 zero4 = {0.f, 0.f, 0.f, 0.f};
  const int nb = (SEGLEN + WARM) / SB;   // 32

  float cA = 0.f, cB = 0.f;
  for (int i = tid; i < 4 * 128; i += 256) hhist[1][SB - 1][i >> 7][i & 127] = 0;

  // prologue: stage sub-block 0 (16 chunks of 1 KB; 4 issues/wave)
#pragma unroll
  for (int i = 0; i < 4; ++i) {
    const int chunk = i * 4 + w;
    const int row = chunk >> 2, sg = chunk & 3;
    int t = (s0 + sg) * SEGLEN - WARM + row;
    t = t < 0 ? 0 : t;
    load_lds16(pre + (size_t)t * 512 + l * 8, &preb[0][row][sg][0]);
  }
  asm volatile("s_waitcnt vmcnt(0) lgkmcnt(0)" ::: "memory");
  __builtin_amdgcn_sched_barrier(0);
  __builtin_amdgcn_s_barrier();
  __builtin_amdgcn_sched_barrier(0);

  for (int bi = 0; bi < nb; ++bi) {
    const int pb = bi & 1;
    if (bi + 1 < nb) {
#pragma unroll
      for (int i = 0; i < 4; ++i) {
        const int chunk = i * 4 + w;
        const int row = chunk >> 2, sg = chunk & 3;
        int t = (s0 + sg) * SEGLEN - WARM + (bi + 1) * SB + row;
        t = t < 0 ? 0 : t;
        load_lds16(pre + (size_t)t * 512 + l * 8, &preb[pb ^ 1][row][sg][0]);
      }
    }
    if (bi >= WARM / SB + 1) {  // flush sub-block bi-1
      const int lt0 = (bi - 1) * SB - WARM;
      const int frow = tid >> 6, fsl = (tid >> 4) & 3, foc = tid & 15;
      const ushort8 hv = *reinterpret_cast<const ushort8*>(&hhist[pb ^ 1][frow][fsl][foc * 8]);
      *reinterpret_cast<ushort8*>(
          hout + ((size_t)(s0 + fsl) * SEGLEN + lt0 + frow) * 128 + foc * 8) = hv;
    }

    for (int s = 0; s < SB; ++s) {
      const int lt = bi * SB + s - WARM;
      const unsigned short* hr = s ? &hhist[pb][s - 1][sl][0] : &hhist[pb ^ 1][SB - 1][sl][0];
      short8 bh[4];
#pragma unroll
      for (int kc = 0; kc < 4; ++kc)
        bh[kc] = *reinterpret_cast<const short8*>(hr + kc * 32 + q * 8);
      const ushort4v pvA = *reinterpret_cast<const ushort4v*>(&preb[pb][s][sl][uA * 4]);
      const ushort4v pvB = *reinterpret_cast<const ushort4v*>(&preb[pb][s][sl][uB * 4]);

#define CHAIN1(ti) \
      f32x4 z##ti; { \
        f32x4 a = __builtin_amdgcn_mfma_f32_16x16x32_bf16(af[ti][0], bh[0], zero4, 0, 0, 0); \
        a = __builtin_amdgcn_mfma_f32_16x16x32_bf16(af[ti][1], bh[1], a, 0, 0, 0); \
        a = __builtin_amdgcn_mfma_f32_16x16x32_bf16(af[ti][2], bh[2], a, 0, 0, 0); \
        z##ti = __builtin_amdgcn_mfma_f32_16x16x32_bf16(af[ti][3], bh[3], a, 0, 0, 0); }
      CHAIN1(0) CHAIN1(1) CHAIN1(2) CHAIN1(3)
      CHAIN1(4) CHAIN1(5) CHAIN1(6) CHAIN1(7)
#undef CHAIN1
      const bool m1 = (r & 1) != 0, m2 = (r & 2) != 0;
      f32x4 zA, zB;
#pragma unroll
      for (int k = 0; k < 4; ++k) {
        const float v01 = m1 ? z1[k] : z0[k];
        const float v23 = m1 ? z3[k] : z2[k];
        zA[k] = m2 ? v23 : v01;
        const float v45 = m1 ? z5[k] : z4[k];
        const float v67 = m1 ? z7[k] : z6[k];
        zB[k] = m2 ? v67 : v45;
      }
      const float igA = sigf(zA[0] + bf2f(pvA[0])), fgA = sigf(zA[1] + bf2f(pvA[1]));
      const float ggA = tanhfast(zA[2] + bf2f(pvA[2])), ogA = sigf(zA[3] + bf2f(pvA[3]));
      cA = fmaf(fgA, cA, igA * ggA);
      float hA = ogA * tanhfast(cA);
      const float igB = sigf(zB[0] + bf2f(pvB[0])), fgB = sigf(zB[1] + bf2f(pvB[1]));
      const float ggB = tanhfast(zB[2] + bf2f(pvB[2])), ogB = sigf(zB[3] + bf2f(pvB[3]));
      cB = fmaf(fgB, cB, igB * ggB);
      float hB = ogB * tanhfast(cB);
      if (zw && lt < 0) { cA = 0.f; cB = 0.f; hA = 0.f; hB = 0.f; }
      hhist[pb][s][sl][uA] = f2bf(hA);
      hhist[pb][s][sl][uB] = f2bf(hB);

      asm volatile("s_waitcnt lgkmcnt(0)" ::: "memory");
      __builtin_amdgcn_sched_barrier(0);
      __builtin_amdgcn_s_barrier();
      __builtin_amdgcn_sched_barrier(0);
    }

    asm volatile("s_waitcnt vmcnt(0)" ::: "memory");
    __builtin_amdgcn_sched_barrier(0);
    __builtin_amdgcn_s_barrier();
    __builtin_amdgcn_sched_barrier(0);
  }

  {  // epilogue flush
    const int pb = (nb - 1) & 1;
    const int lt0 = (nb - 1) * SB - WARM;
    const int frow = tid >> 6, fsl = (tid >> 4) & 3, foc = tid & 15;
    const ushort8 hv = *reinterpret_cast<const ushort8*>(&hhist[pb][frow][fsl][foc * 8]);
    *reinterpret_cast<ushort8*>(
        hout + ((size_t)(s0 + fsl) * SEGLEN + lt0 + frow) * 128 + foc * 8) = hv;
  }
}

// ---------- MFMA MLP block (unchanged)
template<int KI, int KO, bool AFFINE>
__global__ __launch_bounds__(256, 1) void mlp_mfma(
    const unsigned short* __restrict__ in, const float* __restrict__ Wg,
    const float* __restrict__ bias, const float* __restrict__ ac,
    unsigned short* __restrict__ out, float* __restrict__ part)
{
  constexpr int OPR = KI / 8;
  constexpr int NCT = KO / 16;
  constexpr int NKC = KI / 32;
  constexpr int NISS = KI / 16;
  __shared__ __align__(16) unsigned short inr[128 * KI];
  __shared__ __align__(16) unsigned short Wl[KO * KI];
  __shared__ float badj[KO];
  __shared__ float red[4][2][KO];
  const int tid = threadIdx.x;
  const int l = tid & 63, w = tid >> 6;
  const int c = l & 15, q = l >> 4;
  const size_t t0 = (size_t)blockIdx.x * 128;

#pragma unroll
  for (int i = 0; i < NISS; ++i) {
    const int slot = i * 256 + w * 64 + l;
    const int rr = slot / OPR, o = slot % OPR;
    const int so = (o + rr) & (OPR - 1);
    load_lds16(in + (t0 + rr) * KI + so * 8, &inr[(i * 256 + w * 64) * 8]);
  }
  for (int idx = tid; idx < KO * KI; idx += 256) {
    const int n = idx / KI, k = idx % KI;
    float wv = Wg[idx];
    if constexpr (AFFINE) wv *= ac[k];
    const int so = ((k >> 3) + n) & (OPR - 1);
    Wl[n * KI + so * 8 + (k & 7)] = f2bf(wv);
  }
  if (tid < KO) {
    float s = bias[tid];
    if constexpr (AFFINE) {
      for (int k = 0; k < KI; ++k) s = fmaf(Wg[tid * KI + k], ac[KI + k], s);
    }
    badj[tid] = s;
  }
  asm volatile("s_waitcnt vmcnt(0)" ::: "memory");
  __syncthreads();

  short8 bw[NCT][NKC];
#pragma unroll
  for (int ct = 0; ct < NCT; ++ct)
#pragma unroll
    for (int kc = 0; kc < NKC; ++kc) {
      const int o = ((kc * 4 + q) + (ct * 16 + c)) & (OPR - 1);
      bw[ct][kc] = *reinterpret_cast<const short8*>(&Wl[(ct * 16 + c) * KI + o * 8]);
    }

  float psum[NCT], psq[NCT];
#pragma unroll
  for (int ct = 0; ct < NCT; ++ct) { psum[ct] = 0.f; psq[ct] = 0.f; }

#pragma unroll
  for (int rt2 = 0; rt2 < 2; ++rt2) {
    const int rt = w * 2 + rt2;
    short8 afr[NKC];
#pragma unroll
    for (int kc = 0; kc < NKC; ++kc) {
      const int o = ((kc * 4 + q) - c) & (OPR - 1);
      afr[kc] = *reinterpret_cast<const short8*>(&inr[(rt * 16 + c) * KI + o * 8]);
    }
#pragma unroll
    for (int ct = 0; ct < NCT; ++ct) {
      const float bb = badj[ct * 16 + c];
      f32x4 acc = {bb, bb, bb, bb};
#pragma unroll
      for (int kc = 0; kc < NKC; ++kc)
        acc = __builtin_amdgcn_mfma_f32_16x16x32_bf16(afr[kc], bw[ct][kc], acc, 0, 0, 0);
#pragma unroll
      for (int rr = 0; rr < 4; ++rr) {
        float y = acc[rr];
        y = y >= 0.f ? y : 0.01f * y;
        psum[ct] += y; psq[ct] += y * y;
        out[(t0 + rt * 16 + q * 4 + rr) * KO + ct * 16 + c] = f2bf(y);
      }
    }
  }
#pragma unroll
  for (int ct = 0; ct < NCT; ++ct) {
    float s = psum[ct], qq = psq[ct];
    s += __shfl_xor(s, 16); s += __shfl_xor(s, 32);
    qq += __shfl_xor(qq, 16); qq += __shfl_xor(qq, 32);
    if (l < 16) { red[w][0][ct * 16 + c] = s; red[w][1][ct * 16 + c] = qq; }
  }
  __syncthreads();
  if (tid < KO) {
    float s = 0.f, qq = 0.f;
#pragma unroll
    for (int ww = 0; ww < 4; ++ww) { s += red[ww][0][tid]; qq += red[ww][1][tid]; }
    part[(size_t)blockIdx.x * (2 * KO) + tid] = s;
    part[(size_t)blockIdx.x * (2 * KO) + KO + tid] = qq;
  }
}

__global__ __launch_bounds__(1024) void bn_reduce(
    const float* __restrict__ part, const float* __restrict__ gamma,
    const float* __restrict__ beta, float* __restrict__ ac,
    int nblk, int KO, float invT)
{
  __shared__ float tmp[1024];
  const int tid = threadIdx.x;
  const int twoKO = 2 * KO;
  const int ngrp = 1024 / twoKO;
  const int j = tid % twoKO, grp = tid / twoKO;
  float s = 0.f;
  for (int b = grp; b < nblk; b += ngrp) s += part[(size_t)b * twoKO + j];
  tmp[tid] = s;
  __syncthreads();
  if (tid < twoKO) {
    for (int g = 1; g < ngrp; ++g) s += tmp[g * twoKO + tid];
    tmp[tid] = s;
  }
  __syncthreads();
  if (tid < KO) {
    const float m = tmp[tid] * invT;
    const float v = tmp[KO + tid] * invT - m * m;
    const float inv = 1.f / sqrtf(v + 1e-5f);
    const float a = gamma[tid] * inv;
    ac[tid] = a;
    ac[KO + tid] = beta[tid] - m * a;
  }
}

__global__ __launch_bounds__(256) void final_out(
    const unsigned short* __restrict__ y3, const float* __restrict__ wo,
    const float* __restrict__ bo, const float* __restrict__ ac,
    float* __restrict__ out)
{
  const size_t t = (size_t)blockIdx.x * 256 + threadIdx.x;
  float acc = bo[0];
#pragma unroll
  for (int k = 0; k < 16; ++k) acc = fmaf(wo[k], ac[16 + k], acc);
  const ushort8 v0 = reinterpret_cast<const ushort8*>(y3)[t * 2];
  const ushort8 v1 = reinterpret_cast<const ushort8*>(y3)[t * 2 + 1];
#pragma unroll
  for (int k = 0; k < 8; ++k) acc = fmaf(wo[k] * ac[k], bf2f(v0[k]), acc);
#pragma unroll
  for (int k = 0; k < 8; ++k) acc = fmaf(wo[8 + k] * ac[8 + k], bf2f(v1[k]), acc);
  out[t] = acc;
}

extern "C" void kernel_launch(void* const* d_in, const int* in_sizes, int n_in,
                              void* d_out, int out_size, void* d_ws, size_t ws_size,
                              hipStream_t stream) {
  const float* x    = (const float*)d_in[0];
  const float* Wih0 = (const float*)d_in[1];
  const float* Whh0 = (const float*)d_in[2];
  const float* bih0 = (const float*)d_in[3];
  const float* bhh0 = (const float*)d_in[4];
  const float* Wih1 = (const float*)d_in[5];
  const float* Whh1 = (const float*)d_in[6];
  const float* bih1 = (const float*)d_in[7];
  const float* bhh1 = (const float*)d_in[8];
  const float* w1 = (const float*)d_in[9];  const float* b1 = (const float*)d_in[10];
  const float* g1 = (const float*)d_in[11]; const float* be1 = (const float*)d_in[12];
  const float* w2 = (const float*)d_in[13]; const float* b2 = (const float*)d_in[14];
  const float* g2 = (const float*)d_in[15]; const float* be2 = (const float*)d_in[16];
  const float* w3 = (const float*)d_in[17]; const float* b3 = (const float*)d_in[18];
  const float* g3 = (const float*)d_in[19]; const float* be3 = (const float*)d_in[20];
  const float* wo = (const float*)d_in[21]; const float* bo = (const float*)d_in[22];
  float* out = (float*)d_out;

  const int T = T_TOTAL;
  const size_t MB = 1ull << 20;
  char* w8 = (char*)d_ws;
  unsigned short* xpad = (unsigned short*)(w8);              // [T,32]   8MB
  unsigned short* h0   = (unsigned short*)(w8 + 8 * MB);     // [T,128] 32MB
  unsigned short* pre1 = (unsigned short*)(w8 + 40 * MB);    // [T,512] 128MB
  unsigned short* h1   = (unsigned short*)(w8 + 168 * MB);   // [T,128] 32MB
  unsigned short* y1   = (unsigned short*)(w8 + 40 * MB);    // reuse pre1 region
  unsigned short* y2   = (unsigned short*)(w8 + 56 * MB);
  unsigned short* y3   = (unsigned short*)(w8 + 64 * MB);
  float* part1 = (float*)(w8 + 72 * MB);
  float* part2 = (float*)(w8 + 73 * MB);
  float* part3 = (float*)(w8 + 74 * MB);
  float* ac1   = (float*)(w8 + 75 * MB);
  float* ac2   = (float*)(w8 + 75 * MB + 4096);
  float* ac3   = (float*)(w8 + 75 * MB + 8192);

  pad_x<<<T / 256, 256, 0, stream>>>(x, xpad);
  lstm_l0<<<NBLK, 256, 0, stream>>>(xpad, h0, Whh0, Wih0, bih0, bhh0);
  proj512<<<(T / 128) * 4, 256, 0, stream>>>(h0, Wih1, bih1, bhh1, pre1);
  lstm_l1<<<NBLK, 256, 0, stream>>>(pre1, h1, Whh1);

  const int NB = T / 128;
  mlp_mfma<128, 64, false><<<NB, 256, 0, stream>>>(h1, w1, b1, nullptr, y1, part1);
  bn_reduce<<<1, 1024, 0, stream>>>(part1, g1, be1, ac1, NB, 64, 1.f / T);
  mlp_mfma<64, 32, true><<<NB, 256, 0, stream>>>(y1, w2, b2, ac1, y2, part2);
  bn_reduce<<<1, 1024, 0, stream>>>(part2, g2, be2, ac2, NB, 32, 1.f / T);
  mlp_mfma<32, 16, true><<<NB, 256, 0, stream>>>(y2, w3, b3, ac2, y3, part3);
  bn_reduce<<<1, 1024, 0, stream>>>(part3, g3, be3, ac3, NB, 16, 1.f / T);
  final_out<<<T / 256, 256, 0, stream>>>(y3, wo, bo, ac3, out);
}

// Round 15
// 461.862 us; speedup vs baseline: 1.2379x; 1.2379x over previous
//
#include <hip/hip_runtime.h>

#define T_TOTAL 131072
#define SEGLEN  128
#define WARM    64
#define GSEG    4
#define NBLK    (T_TOTAL / (SEGLEN * GSEG))   // 256

typedef __attribute__((ext_vector_type(8))) short short8;
typedef __attribute__((ext_vector_type(8))) unsigned short ushort8;
typedef __attribute__((ext_vector_type(4))) unsigned short ushort4v;
typedef __attribute__((ext_vector_type(4))) float f32x4;

__device__ __forceinline__ float sigf(float x) {
  return __builtin_amdgcn_rcpf(1.f + __expf(-x));
}
__device__ __forceinline__ float tanhfast(float x) {
  return 1.f - 2.f * __builtin_amdgcn_rcpf(__expf(2.f * x) + 1.f);
}
__device__ __forceinline__ unsigned short f2bf(float x) {
  unsigned u = __float_as_uint(x);
  return (unsigned short)((u + 0x7FFFu + ((u >> 16) & 1u)) >> 16);
}
__device__ __forceinline__ float bf2f(unsigned short u) {
  return __uint_as_float(((unsigned)u) << 16);
}
__device__ __forceinline__ void load_lds16(const void* g, void* l) {
  __builtin_amdgcn_global_load_lds(
      (const __attribute__((address_space(1))) void*)g,
      (__attribute__((address_space(3))) void*)l, 16, 0, 0);
}

// ---------- pad x [T][8] f32 -> [T][32] bf16; col 8 = 1.0 (bias rides Wih0)
__global__ __launch_bounds__(256) void pad_x(
    const float* __restrict__ x, unsigned short* __restrict__ xp)
{
  const int t = blockIdx.x * 256 + threadIdx.x;
  const float4 a = reinterpret_cast<const float4*>(x)[t * 2];
  const float4 b = reinterpret_cast<const float4*>(x)[t * 2 + 1];
  ushort8 v;
  v[0] = f2bf(a.x); v[1] = f2bf(a.y); v[2] = f2bf(a.z); v[3] = f2bf(a.w);
  v[4] = f2bf(b.x); v[5] = f2bf(b.y); v[6] = f2bf(b.z); v[7] = f2bf(b.w);
  ushort8 z = {0, 0, 0, 0, 0, 0, 0, 0};
  ushort8 z1 = {0x3F80, 0, 0, 0, 0, 0, 0, 0};
  ushort8* o = reinterpret_cast<ushort8*>(xp) + (size_t)t * 4;
  o[0] = v; o[1] = z1; o[2] = z; o[3] = z;
}

// ---------- layer-0 LSTM, 4 segments per block via MFMA columns.
// MFMA chains INTERLEAVED round-robin (kc outer, ti inner): dependency
// distance 8 issues -> MFMA latency hidden (R13's serial chains = ~1280 cyc
// of exposed latency per step, MfmaUtil 28%).
__global__ __launch_bounds__(256) __attribute__((amdgpu_waves_per_eu(1)))
void lstm_l0(
    const unsigned short* __restrict__ xpad,
    unsigned short* __restrict__ hout,
    const float* __restrict__ Whh, const float* __restrict__ Wih,
    const float* __restrict__ bih, const float* __restrict__ bhh)
{
  constexpr int SB = 32;
  __shared__ __align__(16) unsigned short inbuf[2][SB][4][32];   // 16 KB
  __shared__ __align__(16) unsigned short hhist[2][SB][4][144];  // 72 KB
  const int tid = threadIdx.x;
  const int l = tid & 63, w = tid >> 6;
  const int c = l & 15, q = l >> 4;
  const int sl = c >> 2, r = c & 3;
  const int uA = w * 32 + r * 4 + q;
  const int uB = uA + 16;
  const int s0 = blockIdx.x * GSEG;
  const bool zw = (blockIdx.x == 0) && (sl == 0);

  short8 af[8][4];
#pragma unroll
  for (int ti = 0; ti < 8; ++ti) {
    const int rp = (w * 8 + ti) * 16 + c;
    const int jm = rp >> 2, g = rp & 3;
    const float* wr = Whh + (size_t)(g * 128 + jm) * 128 + q * 8;
#pragma unroll
    for (int kc = 0; kc < 4; ++kc) {
      short8 v;
#pragma unroll
      for (int e = 0; e < 8; ++e) v[e] = (short)f2bf(wr[kc * 32 + e]);
      af[ti][kc] = v;
    }
  }
  short8 afi[8];
#pragma unroll
  for (int ti = 0; ti < 8; ++ti) {
    const int rp = (w * 8 + ti) * 16 + c;
    const int jm = rp >> 2, g = rp & 3;
    short8 v;
#pragma unroll
    for (int e = 0; e < 8; ++e) {
      const int k = q * 8 + e;
      float wv = 0.f;
      if (k < 8) wv = Wih[(size_t)(g * 128 + jm) * 8 + k];
      else if (k == 8) wv = bih[g * 128 + jm] + bhh[g * 128 + jm];
      v[e] = (short)f2bf(wv);
    }
    afi[ti] = v;
  }
  const f32x4 zero4 = {0.f, 0.f, 0.f, 0.f};
  const int nb = (SEGLEN + WARM) / SB;   // 6

  float cA = 0.f, cB = 0.f;
  for (int i = tid; i < 4 * 128; i += 256) hhist[1][SB - 1][i >> 7][i & 127] = 0;

  // prologue: stage sub-block 0
#pragma unroll
  for (int i = 0; i < 2; ++i) {
    const int slot = i * 256 + tid;
    const int row = slot >> 4, sg = (slot >> 2) & 3, oct = slot & 3;
    int t = (s0 + sg) * SEGLEN - WARM + row;
    t = t < 0 ? 0 : t;
    load_lds16(xpad + (size_t)t * 32 + oct * 8,
               &inbuf[0][0][0][0] + (size_t)(i * 256 + w * 64) * 8);
  }
  asm volatile("s_waitcnt vmcnt(0) lgkmcnt(0)" ::: "memory");
  __builtin_amdgcn_sched_barrier(0);
  __builtin_amdgcn_s_barrier();
  __builtin_amdgcn_sched_barrier(0);

  for (int bi = 0; bi < nb; ++bi) {
    const int pb = bi & 1;
    if (bi + 1 < nb) {
#pragma unroll
      for (int i = 0; i < 2; ++i) {
        const int slot = i * 256 + tid;
        const int row = slot >> 4, sg = (slot >> 2) & 3, oct = slot & 3;
        int t = (s0 + sg) * SEGLEN - WARM + (bi + 1) * SB + row;
        t = t < 0 ? 0 : t;
        load_lds16(xpad + (size_t)t * 32 + oct * 8,
                   &inbuf[pb ^ 1][0][0][0] + (size_t)(i * 256 + w * 64) * 8);
      }
    }
    if (bi >= 3) {
      const int lt0 = (bi - 1) * SB - WARM;
#pragma unroll
      for (int it = 0; it < 8; ++it) {
        const int slot = it * 256 + tid;
        const int fsl = slot >> 9, frow = (slot >> 4) & 31, foc = slot & 15;
        const ushort8 hv = *reinterpret_cast<const ushort8*>(&hhist[pb ^ 1][frow][fsl][foc * 8]);
        *reinterpret_cast<ushort8*>(
            hout + ((size_t)(s0 + fsl) * SEGLEN + lt0 + frow) * 128 + foc * 8) = hv;
      }
    }

    for (int s = 0; s < SB; ++s) {
      const int lt = bi * SB + s - WARM;
      const unsigned short* hr = s ? &hhist[pb][s - 1][sl][0] : &hhist[pb ^ 1][SB - 1][sl][0];
      short8 bh[4];
#pragma unroll
      for (int kc = 0; kc < 4; ++kc)
        bh[kc] = *reinterpret_cast<const short8*>(hr + kc * 32 + q * 8);
      const short8 bx = *reinterpret_cast<const short8*>(&inbuf[pb][s][sl][q * 8]);

      // interleaved rounds: 8 independent accumulator chains
      f32x4 z0, z1, z2, z3, z4, z5, z6, z7;
      z0 = __builtin_amdgcn_mfma_f32_16x16x32_bf16(afi[0], bx, zero4, 0, 0, 0);
      z1 = __builtin_amdgcn_mfma_f32_16x16x32_bf16(afi[1], bx, zero4, 0, 0, 0);
      z2 = __builtin_amdgcn_mfma_f32_16x16x32_bf16(afi[2], bx, zero4, 0, 0, 0);
      z3 = __builtin_amdgcn_mfma_f32_16x16x32_bf16(afi[3], bx, zero4, 0, 0, 0);
      z4 = __builtin_amdgcn_mfma_f32_16x16x32_bf16(afi[4], bx, zero4, 0, 0, 0);
      z5 = __builtin_amdgcn_mfma_f32_16x16x32_bf16(afi[5], bx, zero4, 0, 0, 0);
      z6 = __builtin_amdgcn_mfma_f32_16x16x32_bf16(afi[6], bx, zero4, 0, 0, 0);
      z7 = __builtin_amdgcn_mfma_f32_16x16x32_bf16(afi[7], bx, zero4, 0, 0, 0);
#define ROUND(kc) \
      z0 = __builtin_amdgcn_mfma_f32_16x16x32_bf16(af[0][kc], bh[kc], z0, 0, 0, 0); \
      z1 = __builtin_amdgcn_mfma_f32_16x16x32_bf16(af[1][kc], bh[kc], z1, 0, 0, 0); \
      z2 = __builtin_amdgcn_mfma_f32_16x16x32_bf16(af[2][kc], bh[kc], z2, 0, 0, 0); \
      z3 = __builtin_amdgcn_mfma_f32_16x16x32_bf16(af[3][kc], bh[kc], z3, 0, 0, 0); \
      z4 = __builtin_amdgcn_mfma_f32_16x16x32_bf16(af[4][kc], bh[kc], z4, 0, 0, 0); \
      z5 = __builtin_amdgcn_mfma_f32_16x16x32_bf16(af[5][kc], bh[kc], z5, 0, 0, 0); \
      z6 = __builtin_amdgcn_mfma_f32_16x16x32_bf16(af[6][kc], bh[kc], z6, 0, 0, 0); \
      z7 = __builtin_amdgcn_mfma_f32_16x16x32_bf16(af[7][kc], bh[kc], z7, 0, 0, 0);
      ROUND(0) ROUND(1) ROUND(2) ROUND(3)
#undef ROUND
      const bool m1 = (r & 1) != 0, m2 = (r & 2) != 0;
      f32x4 zA, zB;
#pragma unroll
      for (int k = 0; k < 4; ++k) {
        const float v01 = m1 ? z1[k] : z0[k];
        const float v23 = m1 ? z3[k] : z2[k];
        zA[k] = m2 ? v23 : v01;
        const float v45 = m1 ? z5[k] : z4[k];
        const float v67 = m1 ? z7[k] : z6[k];
        zB[k] = m2 ? v67 : v45;
      }
      const float igA = sigf(zA[0]), fgA = sigf(zA[1]);
      const float ggA = tanhfast(zA[2]), ogA = sigf(zA[3]);
      cA = fmaf(fgA, cA, igA * ggA);
      float hA = ogA * tanhfast(cA);
      const float igB = sigf(zB[0]), fgB = sigf(zB[1]);
      const float ggB = tanhfast(zB[2]), ogB = sigf(zB[3]);
      cB = fmaf(fgB, cB, igB * ggB);
      float hB = ogB * tanhfast(cB);
      if (zw && lt < 0) { cA = 0.f; cB = 0.f; hA = 0.f; hB = 0.f; }
      hhist[pb][s][sl][uA] = f2bf(hA);
      hhist[pb][s][sl][uB] = f2bf(hB);

      asm volatile("s_waitcnt lgkmcnt(0)" ::: "memory");
      __builtin_amdgcn_sched_barrier(0);
      __builtin_amdgcn_s_barrier();
      __builtin_amdgcn_sched_barrier(0);
    }

    asm volatile("s_waitcnt vmcnt(0)" ::: "memory");
    __builtin_amdgcn_sched_barrier(0);
    __builtin_amdgcn_s_barrier();
    __builtin_amdgcn_sched_barrier(0);
  }

  {
    const int pb = (nb - 1) & 1;
    const int lt0 = (nb - 1) * SB - WARM;
#pragma unroll
    for (int it = 0; it < 8; ++it) {
      const int slot = it * 256 + tid;
      const int fsl = slot >> 9, frow = (slot >> 4) & 31, foc = slot & 15;
      const ushort8 hv = *reinterpret_cast<const ushort8*>(&hhist[pb][frow][fsl][foc * 8]);
      *reinterpret_cast<ushort8*>(
          hout + ((size_t)(s0 + fsl) * SEGLEN + lt0 + frow) * 128 + foc * 8) = hv;
    }
  }
}

// ---------- pre1 projection: pre1[t][rp] = Wih1_perm@h0 + bias (bf16 out)
__global__ __launch_bounds__(256) void proj512(
    const unsigned short* __restrict__ h0, const float* __restrict__ Wih,
    const float* __restrict__ bih, const float* __restrict__ bhh,
    unsigned short* __restrict__ pre1)
{
  __shared__ __align__(16) unsigned short inr[128 * 128];
  __shared__ __align__(16) unsigned short Wl[128 * 128];
  __shared__ float badj[128];
  const int tid = threadIdx.x;
  const int l = tid & 63, w = tid >> 6;
  const int c = l & 15, q = l >> 4;
  const int tb = blockIdx.x >> 2, cb = blockIdx.x & 3;
  const size_t t0 = (size_t)tb * 128;

#pragma unroll
  for (int i = 0; i < 8; ++i) {
    const int slot = i * 256 + tid;
    const int rr = slot >> 4, o = slot & 15;
    const int so = (o + rr) & 15;
    load_lds16(h0 + (t0 + rr) * 128 + so * 8, &inr[0] + (i * 256 + (tid & ~63)) * 8);
  }
  for (int idx = tid; idx < 128 * 128; idx += 256) {
    const int n = idx >> 7, k = idx & 127;
    const int rp = cb * 128 + n;
    const int jm = rp >> 2, g = rp & 3;
    const float wv = Wih[(size_t)(g * 128 + jm) * 128 + k];
    const int so = ((k >> 3) + n) & 15;
    Wl[n * 128 + so * 8 + (k & 7)] = f2bf(wv);
  }
  if (tid < 128) {
    const int rp = cb * 128 + tid;
    const int jm = rp >> 2, g = rp & 3;
    badj[tid] = bih[g * 128 + jm] + bhh[g * 128 + jm];
  }
  asm volatile("s_waitcnt vmcnt(0)" ::: "memory");
  __syncthreads();

  short8 bw[8][4];
#pragma unroll
  for (int ct = 0; ct < 8; ++ct)
#pragma unroll
    for (int kc = 0; kc < 4; ++kc) {
      const int o = ((kc * 4 + q) + (ct * 16 + c)) & 15;
      bw[ct][kc] = *reinterpret_cast<const short8*>(&Wl[(ct * 16 + c) * 128 + o * 8]);
    }

#pragma unroll
  for (int rt2 = 0; rt2 < 2; ++rt2) {
    const int rt = w * 2 + rt2;
    short8 afr[4];
#pragma unroll
    for (int kc = 0; kc < 4; ++kc) {
      const int o = ((kc * 4 + q) - c) & 15;
      afr[kc] = *reinterpret_cast<const short8*>(&inr[(rt * 16 + c) * 128 + o * 8]);
    }
#pragma unroll
    for (int ct = 0; ct < 8; ++ct) {
      const float bb = badj[ct * 16 + c];
      f32x4 acc = {bb, bb, bb, bb};
#pragma unroll
      for (int kc = 0; kc < 4; ++kc)
        acc = __builtin_amdgcn_mfma_f32_16x16x32_bf16(afr[kc], bw[ct][kc], acc, 0, 0, 0);
#pragma unroll
      for (int rr = 0; rr < 4; ++rr)
        pre1[(t0 + rt * 16 + q * 4 + rr) * 512 + cb * 128 + ct * 16 + c] = f2bf(acc[rr]);
    }
  }
}

// ---------- layer-1 LSTM, 4 segments per block; SB=8, padded preb rows (520).
__global__ __launch_bounds__(256) __attribute__((amdgpu_waves_per_eu(1)))
void lstm_l1(
    const unsigned short* __restrict__ pre,
    unsigned short* __restrict__ hout,
    const float* __restrict__ Whh)
{
  constexpr int SB = 8;
  __shared__ __align__(16) unsigned short preb[2][SB][4][520];   // 66.6 KB, pad kills 4-way
  __shared__ __align__(16) unsigned short hhist[2][SB][4][144];  // 18.4 KB
  const int tid = threadIdx.x;
  const int l = tid & 63, w = tid >> 6;
  const int c = l & 15, q = l >> 4;
  const int sl = c >> 2, r = c & 3;
  const int uA = w * 32 + r * 4 + q;
  const int uB = uA + 16;
  const int s0 = blockIdx.x * GSEG;
  const bool zw = (blockIdx.x == 0) && (sl == 0);

  short8 af[8][4];
#pragma unroll
  for (int ti = 0; ti < 8; ++ti) {
    const int rp = (w * 8 + ti) * 16 + c;
    const int jm = rp >> 2, g = rp & 3;
    const float* wr = Whh + (size_t)(g * 128 + jm) * 128 + q * 8;
#pragma unroll
    for (int kc = 0; kc < 4; ++kc) {
      short8 v;
#pragma unroll
      for (int e = 0; e < 8; ++e) v[e] = (short)f2bf(wr[kc * 32 + e]);
      af[ti][kc] = v;
    }
  }
  const f32x4 zero4 = {0.f, 0.f, 0.f, 0.f};
  const int nb = (SEGLEN + WARM) / SB;   // 24

  float cA = 0.f, cB = 0.f;
  for (int i = tid; i < 4 * 128; i += 256) hhist[1][SB - 1][i >> 7][i & 127] = 0;

  // prologue: stage sub-block 0 (32 chunks of 1 KB; 8 issues/wave)
#pragma unroll
  for (int i = 0; i < 8; ++i) {
    const int chunk = i * 4 + w;
    const int row = chunk >> 2, sg = chunk & 3;
    int t = (s0 + sg) * SEGLEN - WARM + row;
    t = t < 0 ? 0 : t;
    load_lds16(pre + (size_t)t * 512 + l * 8, &preb[0][row][sg][0]);
  }
  asm volatile("s_waitcnt vmcnt(0) lgkmcnt(0)" ::: "memory");
  __builtin_amdgcn_sched_barrier(0);
  __builtin_amdgcn_s_barrier();
  __builtin_amdgcn_sched_barrier(0);

  for (int bi = 0; bi < nb; ++bi) {
    const int pb = bi & 1;
    if (bi + 1 < nb) {
#pragma unroll
      for (int i = 0; i < 8; ++i) {
        const int chunk = i * 4 + w;
        const int row = chunk >> 2, sg = chunk & 3;
        int t = (s0 + sg) * SEGLEN - WARM + (bi + 1) * SB + row;
        t = t < 0 ? 0 : t;
        load_lds16(pre + (size_t)t * 512 + l * 8, &preb[pb ^ 1][row][sg][0]);
      }
    }
    if (bi >= WARM / SB + 1) {
      const int lt0 = (bi - 1) * SB - WARM;
#pragma unroll
      for (int it = 0; it < 2; ++it) {
        const int slot = it * 256 + tid;
        const int fsl = slot >> 7, frow = (slot >> 4) & 7, foc = slot & 15;
        const ushort8 hv = *reinterpret_cast<const ushort8*>(&hhist[pb ^ 1][frow][fsl][foc * 8]);
        *reinterpret_cast<ushort8*>(
            hout + ((size_t)(s0 + fsl) * SEGLEN + lt0 + frow) * 128 + foc * 8) = hv;
      }
    }

    for (int s = 0; s < SB; ++s) {
      const int lt = bi * SB + s - WARM;
      const unsigned short* hr = s ? &hhist[pb][s - 1][sl][0] : &hhist[pb ^ 1][SB - 1][sl][0];
      short8 bh[4];
#pragma unroll
      for (int kc = 0; kc < 4; ++kc)
        bh[kc] = *reinterpret_cast<const short8*>(hr + kc * 32 + q * 8);
      const ushort4v pvA = *reinterpret_cast<const ushort4v*>(&preb[pb][s][sl][uA * 4]);
      const ushort4v pvB = *reinterpret_cast<const ushort4v*>(&preb[pb][s][sl][uB * 4]);

      // interleaved rounds
      f32x4 z0, z1, z2, z3, z4, z5, z6, z7;
      z0 = __builtin_amdgcn_mfma_f32_16x16x32_bf16(af[0][0], bh[0], zero4, 0, 0, 0);
      z1 = __builtin_amdgcn_mfma_f32_16x16x32_bf16(af[1][0], bh[0], zero4, 0, 0, 0);
      z2 = __builtin_amdgcn_mfma_f32_16x16x32_bf16(af[2][0], bh[0], zero4, 0, 0, 0);
      z3 = __builtin_amdgcn_mfma_f32_16x16x32_bf16(af[3][0], bh[0], zero4, 0, 0, 0);
      z4 = __builtin_amdgcn_mfma_f32_16x16x32_bf16(af[4][0], bh[0], zero4, 0, 0, 0);
      z5 = __builtin_amdgcn_mfma_f32_16x16x32_bf16(af[5][0], bh[0], zero4, 0, 0, 0);
      z6 = __builtin_amdgcn_mfma_f32_16x16x32_bf16(af[6][0], bh[0], zero4, 0, 0, 0);
      z7 = __builtin_amdgcn_mfma_f32_16x16x32_bf16(af[7][0], bh[0], zero4, 0, 0, 0);
#define ROUND(kc) \
      z0 = __builtin_amdgcn_mfma_f32_16x16x32_bf16(af[0][kc], bh[kc], z0, 0, 0, 0); \
      z1 = __builtin_amdgcn_mfma_f32_16x16x32_bf16(af[1][kc], bh[kc], z1, 0, 0, 0); \
      z2 = __builtin_amdgcn_mfma_f32_16x16x32_bf16(af[2][kc], bh[kc], z2, 0, 0, 0); \
      z3 = __builtin_amdgcn_mfma_f32_16x16x32_bf16(af[3][kc], bh[kc], z3, 0, 0, 0); \
      z4 = __builtin_amdgcn_mfma_f32_16x16x32_bf16(af[4][kc], bh[kc], z4, 0, 0, 0); \
      z5 = __builtin_amdgcn_mfma_f32_16x16x32_bf16(af[5][kc], bh[kc], z5, 0, 0, 0); \
      z6 = __builtin_amdgcn_mfma_f32_16x16x32_bf16(af[6][kc], bh[kc], z6, 0, 0, 0); \
      z7 = __builtin_amdgcn_mfma_f32_16x16x32_bf16(af[7][kc], bh[kc], z7, 0, 0, 0);
      ROUND(1) ROUND(2) ROUND(3)
#undef ROUND
      const bool m1 = (r & 1) != 0, m2 = (r & 2) != 0;
      f32x4 zA, zB;
#pragma unroll
      for (int k = 0; k < 4; ++k) {
        const float v01 = m1 ? z1[k] : z0[k];
        const float v23 = m1 ? z3[k] : z2[k];
        zA[k] = m2 ? v23 : v01;
        const float v45 = m1 ? z5[k] : z4[k];
        const float v67 = m1 ? z7[k] : z6[k];
        zB[k] = m2 ? v67 : v45;
      }
      const float igA = sigf(zA[0] + bf2f(pvA[0])), fgA = sigf(zA[1] + bf2f(pvA[1]));
      const float ggA = tanhfast(zA[2] + bf2f(pvA[2])), ogA = sigf(zA[3] + bf2f(pvA[3]));
      cA = fmaf(fgA, cA, igA * ggA);
      float hA = ogA * tanhfast(cA);
      const float igB = sigf(zB[0] + bf2f(pvB[0])), fgB = sigf(zB[1] + bf2f(pvB[1]));
      const float ggB = tanhfast(zB[2] + bf2f(pvB[2])), ogB = sigf(zB[3] + bf2f(pvB[3]));
      cB = fmaf(fgB, cB, igB * ggB);
      float hB = ogB * tanhfast(cB);
      if (zw && lt < 0) { cA = 0.f; cB = 0.f; hA = 0.f; hB = 0.f; }
      hhist[pb][s][sl][uA] = f2bf(hA);
      hhist[pb][s][sl][uB] = f2bf(hB);

      asm volatile("s_waitcnt lgkmcnt(0)" ::: "memory");
      __builtin_amdgcn_sched_barrier(0);
      __builtin_amdgcn_s_barrier();
      __builtin_amdgcn_sched_barrier(0);
    }

    asm volatile("s_waitcnt vmcnt(0)" ::: "memory");
    __builtin_amdgcn_sched_barrier(0);
    __builtin_amdgcn_s_barrier();
    __builtin_amdgcn_sched_barrier(0);
  }

  {
    const int pb = (nb - 1) & 1;
    const int lt0 = (nb - 1) * SB - WARM;
#pragma unroll
    for (int it = 0; it < 2; ++it) {
      const int slot = it * 256 + tid;
      const int fsl = slot >> 7, frow = (slot >> 4) & 7, foc = slot & 15;
      const ushort8 hv = *reinterpret_cast<const ushort8*>(&hhist[pb][frow][fsl][foc * 8]);
      *reinterpret_cast<ushort8*>(
          hout + ((size_t)(s0 + fsl) * SEGLEN + lt0 + frow) * 128 + foc * 8) = hv;
    }
  }
}

// ---------- MFMA MLP block (unchanged)
template<int KI, int KO, bool AFFINE>
__global__ __launch_bounds__(256, 1) void mlp_mfma(
    const unsigned short* __restrict__ in, const float* __restrict__ Wg,
    const float* __restrict__ bias, const float* __restrict__ ac,
    unsigned short* __restrict__ out, float* __restrict__ part)
{
  constexpr int OPR = KI / 8;
  constexpr int NCT = KO / 16;
  constexpr int NKC = KI / 32;
  constexpr int NISS = KI / 16;
  __shared__ __align__(16) unsigned short inr[128 * KI];
  __shared__ __align__(16) unsigned short Wl[KO * KI];
  __shared__ float badj[KO];
  __shared__ float red[4][2][KO];
  const int tid = threadIdx.x;
  const int l = tid & 63, w = tid >> 6;
  const int c = l & 15, q = l >> 4;
  const size_t t0 = (size_t)blockIdx.x * 128;

#pragma unroll
  for (int i = 0; i < NISS; ++i) {
    const int slot = i * 256 + w * 64 + l;
    const int rr = slot / OPR, o = slot % OPR;
    const int so = (o + rr) & (OPR - 1);
    load_lds16(in + (t0 + rr) * KI + so * 8, &inr[(i * 256 + w * 64) * 8]);
  }
  for (int idx = tid; idx < KO * KI; idx += 256) {
    const int n = idx / KI, k = idx % KI;
    float wv = Wg[idx];
    if constexpr (AFFINE) wv *= ac[k];
    const int so = ((k >> 3) + n) & (OPR - 1);
    Wl[n * KI + so * 8 + (k & 7)] = f2bf(wv);
  }
  if (tid < KO) {
    float s = bias[tid];
    if constexpr (AFFINE) {
      for (int k = 0; k < KI; ++k) s = fmaf(Wg[tid * KI + k], ac[KI + k], s);
    }
    badj[tid] = s;
  }
  asm volatile("s_waitcnt vmcnt(0)" ::: "memory");
  __syncthreads();

  short8 bw[NCT][NKC];
#pragma unroll
  for (int ct = 0; ct < NCT; ++ct)
#pragma unroll
    for (int kc = 0; kc < NKC; ++kc) {
      const int o = ((kc * 4 + q) + (ct * 16 + c)) & (OPR - 1);
      bw[ct][kc] = *reinterpret_cast<const short8*>(&Wl[(ct * 16 + c) * KI + o * 8]);
    }

  float psum[NCT], psq[NCT];
#pragma unroll
  for (int ct = 0; ct < NCT; ++ct) { psum[ct] = 0.f; psq[ct] = 0.f; }

#pragma unroll
  for (int rt2 = 0; rt2 < 2; ++rt2) {
    const int rt = w * 2 + rt2;
    short8 afr[NKC];
#pragma unroll
    for (int kc = 0; kc < NKC; ++kc) {
      const int o = ((kc * 4 + q) - c) & (OPR - 1);
      afr[kc] = *reinterpret_cast<const short8*>(&inr[(rt * 16 + c) * KI + o * 8]);
    }
#pragma unroll
    for (int ct = 0; ct < NCT; ++ct) {
      const float bb = badj[ct * 16 + c];
      f32x4 acc = {bb, bb, bb, bb};
#pragma unroll
      for (int kc = 0; kc < NKC; ++kc)
        acc = __builtin_amdgcn_mfma_f32_16x16x32_bf16(afr[kc], bw[ct][kc], acc, 0, 0, 0);
#pragma unroll
      for (int rr = 0; rr < 4; ++rr) {
        float y = acc[rr];
        y = y >= 0.f ? y : 0.01f * y;
        psum[ct] += y; psq[ct] += y * y;
        out[(t0 + rt * 16 + q * 4 + rr) * KO + ct * 16 + c] = f2bf(y);
      }
    }
  }
#pragma unroll
  for (int ct = 0; ct < NCT; ++ct) {
    float s = psum[ct], qq = psq[ct];
    s += __shfl_xor(s, 16); s += __shfl_xor(s, 32);
    qq += __shfl_xor(qq, 16); qq += __shfl_xor(qq, 32);
    if (l < 16) { red[w][0][ct * 16 + c] = s; red[w][1][ct * 16 + c] = qq; }
  }
  __syncthreads();
  if (tid < KO) {
    float s = 0.f, qq = 0.f;
#pragma unroll
    for (int ww = 0; ww < 4; ++ww) { s += red[ww][0][tid]; qq += red[ww][1][tid]; }
    part[(size_t)blockIdx.x * (2 * KO) + tid] = s;
    part[(size_t)blockIdx.x * (2 * KO) + KO + tid] = qq;
  }
}

__global__ __launch_bounds__(1024) void bn_reduce(
    const float* __restrict__ part, const float* __restrict__ gamma,
    const float* __restrict__ beta, float* __restrict__ ac,
    int nblk, int KO, float invT)
{
  __shared__ float tmp[1024];
  const int tid = threadIdx.x;
  const int twoKO = 2 * KO;
  const int ngrp = 1024 / twoKO;
  const int j = tid % twoKO, grp = tid / twoKO;
  float s = 0.f;
  for (int b = grp; b < nblk; b += ngrp) s += part[(size_t)b * twoKO + j];
  tmp[tid] = s;
  __syncthreads();
  if (tid < twoKO) {
    for (int g = 1; g < ngrp; ++g) s += tmp[g * twoKO + tid];
    tmp[tid] = s;
  }
  __syncthreads();
  if (tid < KO) {
    const float m = tmp[tid] * invT;
    const float v = tmp[KO + tid] * invT - m * m;
    const float inv = 1.f / sqrtf(v + 1e-5f);
    const float a = gamma[tid] * inv;
    ac[tid] = a;
    ac[KO + tid] = beta[tid] - m * a;
  }
}

__global__ __launch_bounds__(256) void final_out(
    const unsigned short* __restrict__ y3, const float* __restrict__ wo,
    const float* __restrict__ bo, const float* __restrict__ ac,
    float* __restrict__ out)
{
  const size_t t = (size_t)blockIdx.x * 256 + threadIdx.x;
  float acc = bo[0];
#pragma unroll
  for (int k = 0; k < 16; ++k) acc = fmaf(wo[k], ac[16 + k], acc);
  const ushort8 v0 = reinterpret_cast<const ushort8*>(y3)[t * 2];
  const ushort8 v1 = reinterpret_cast<const ushort8*>(y3)[t * 2 + 1];
#pragma unroll
  for (int k = 0; k < 8; ++k) acc = fmaf(wo[k] * ac[k], bf2f(v0[k]), acc);
#pragma unroll
  for (int k = 0; k < 8; ++k) acc = fmaf(wo[8 + k] * ac[8 + k], bf2f(v1[k]), acc);
  out[t] = acc;
}

extern "C" void kernel_launch(void* const* d_in, const int* in_sizes, int n_in,
                              void* d_out, int out_size, void* d_ws, size_t ws_size,
                              hipStream_t stream) {
  const float* x    = (const float*)d_in[0];
  const float* Wih0 = (const float*)d_in[1];
  const float* Whh0 = (const float*)d_in[2];
  const float* bih0 = (const float*)d_in[3];
  const float* bhh0 = (const float*)d_in[4];
  const float* Wih1 = (const float*)d_in[5];
  const float* Whh1 = (const float*)d_in[6];
  const float* bih1 = (const float*)d_in[7];
  const float* bhh1 = (const float*)d_in[8];
  const float* w1 = (const float*)d_in[9];  const float* b1 = (const float*)d_in[10];
  const float* g1 = (const float*)d_in[11]; const float* be1 = (const float*)d_in[12];
  const float* w2 = (const float*)d_in[13]; const float* b2 = (const float*)d_in[14];
  const float* g2 = (const float*)d_in[15]; const float* be2 = (const float*)d_in[16];
  const float* w3 = (const float*)d_in[17]; const float* b3 = (const float*)d_in[18];
  const float* g3 = (const float*)d_in[19]; const float* be3 = (const float*)d_in[20];
  const float* wo = (const float*)d_in[21]; const float* bo = (const float*)d_in[22];
  float* out = (float*)d_out;

  const int T = T_TOTAL;
  const size_t MB = 1ull << 20;
  char* w8 = (char*)d_ws;
  unsigned short* xpad = (unsigned short*)(w8);              // [T,32]   8MB
  unsigned short* h0   = (unsigned short*)(w8 + 8 * MB);     // [T,128] 32MB
  unsigned short* pre1 = (unsigned short*)(w8 + 40 * MB);    // [T,512] 128MB
  unsigned short* h1   = (unsigned short*)(w8 + 168 * MB);   // [T,128] 32MB
  unsigned short* y1   = (unsigned short*)(w8 + 40 * MB);    // reuse pre1 region
  unsigned short* y2   = (unsigned short*)(w8 + 56 * MB);
  unsigned short* y3   = (unsigned short*)(w8 + 64 * MB);
  float* part1 = (float*)(w8 + 72 * MB);
  float* part2 = (float*)(w8 + 73 * MB);
  float* part3 = (float*)(w8 + 74 * MB);
  float* ac1   = (float*)(w8 + 75 * MB);
  float* ac2   = (float*)(w8 + 75 * MB + 4096);
  float* ac3   = (float*)(w8 + 75 * MB + 8192);

  pad_x<<<T / 256, 256, 0, stream>>>(x, xpad);
  lstm_l0<<<NBLK, 256, 0, stream>>>(xpad, h0, Whh0, Wih0, bih0, bhh0);
  proj512<<<(T / 128) * 4, 256, 0, stream>>>(h0, Wih1, bih1, bhh1, pre1);
  lstm_l1<<<NBLK, 256, 0, stream>>>(pre1, h1, Whh1);

  const int NB = T / 128;
  mlp_mfma<128, 64, false><<<NB, 256, 0, stream>>>(h1, w1, b1, nullptr, y1, part1);
  bn_reduce<<<1, 1024, 0, stream>>>(part1, g1, be1, ac1, NB, 64, 1.f / T);
  mlp_mfma<64, 32, true><<<NB, 256, 0, stream>>>(y1, w2, b2, ac1, y2, part2);
  bn_reduce<<<1, 1024, 0, stream>>>(part2, g2, be2, ac2, NB, 32, 1.f / T);
  mlp_mfma<32, 16, true><<<NB, 256, 0, stream>>>(y2, w3, b3, ac2, y3, part3);
  bn_reduce<<<1, 1024, 0, stream>>>(part3, g3, be3, ac3, NB, 16, 1.f / T);
  final_out<<<T / 256, 256, 0, stream>>>(y3, wo, bo, ac3, out);
}